// Round 1
// baseline (195548.022 us; speedup 1.0000x reference)
//
#include <hip/hip_runtime.h>

// Echo-state network recurrence on MI355X.
// Latency-bound design: 32 persistent WGs, weights in VGPRs, state exchanged
// through IF$ with self-validating (value,tag) 8B atomic pairs. No fences,
// no grid barrier: tag==step makes every element its own flag.

#define HH   1024
#define TT   50000
#define WASH 200
#define NWG  32     // workgroups; WG g owns rows [32g, 32g+32)
#define NT   512    // threads/WG: chunk c = tid>>4 (32 cols each), slot p = tid&15 -> rows p, p+16

__device__ __forceinline__ float fast_tanh(float x) {
  // tanh(x) = 1 - 2/(exp2(2x*log2e)+1); safe at +/-inf (no NaN).
  float e = __builtin_amdgcn_exp2f(x * 2.8853900817779268f);
  return fmaf(-2.0f, __builtin_amdgcn_rcpf(e + 1.0f), 1.0f);
}

__global__ __launch_bounds__(NT, 2) void esn_kernel(
    const float* __restrict__ u,
    const float* __restrict__ w_in,
    const float* __restrict__ w_res,
    const float* __restrict__ w_out,
    const int*   __restrict__ mask,
    float*       __restrict__ out,
    unsigned long long* __restrict__ xws)   // 2 * HH tagged pairs (16 KiB)
{
  const int g   = blockIdx.x;
  const int tid = threadIdx.x;
  const int c   = tid >> 4;   // column chunk 0..31, cols [32c, 32c+32)
  const int p   = tid & 15;   // rows p and p+16 (local)

  __shared__ float pbuf[2][32][33];  // [parity][chunk][row], +1 pad kills 4-way conflict
  __shared__ float lds_c[HH];

  // readout coefficients: c[mask[h]] = w_out[h]  (LDS-only => no coherence issues)
  for (int h = tid; h < HH; h += NT) lds_c[mask[h]] = w_out[h];
  __syncthreads();

  // weights resident in VGPRs: 2 rows x 32 cols per thread
  const int row0 = g * 32 + p;
  const int row1 = row0 + 16;
  float w0[32], w1[32];
  {
    const float4* a = (const float4*)(w_res + (size_t)row0 * HH + c * 32);
    const float4* b = (const float4*)(w_res + (size_t)row1 * HH + c * 32);
#pragma unroll
    for (int q = 0; q < 8; ++q) {
      float4 va = a[q], vb = b[q];
      w0[4*q+0]=va.x; w0[4*q+1]=va.y; w0[4*q+2]=va.z; w0[4*q+3]=va.w;
      w1[4*q+0]=vb.x; w1[4*q+1]=vb.y; w1[4*q+2]=vb.z; w1[4*q+3]=vb.w;
    }
  }

  // epilogue-lane preloads (wave 0, lanes 0..31 handle rows 0..31)
  float win_r = 0.f, c_r = 0.f;
  if (tid < 32) {
    win_r = w_in[g * 32 + tid];
    c_r   = lds_c[g * 32 + tid];
  }
  __syncthreads();

  unsigned long long* xb0 = xws;        // parity-0 buffer
  unsigned long long* xb1 = xws + HH;   // parity-1 buffer
  const int cbase = c * 32;

  for (int t = 0; t < TT; ++t) {
    const int pa = t & 1;
    const float u_t = u[t];             // uniform scalar load, overlaps poll
    float a0 = 0.f, a1 = 0.f, a2 = 0.f, a3 = 0.f;

    if (t > 0) {
      unsigned long long* src = pa ? xb0 : xb1;      // buf[(t-1)&1]
      const unsigned int want = (unsigned int)t;     // tag of x_{t-1} is t
      unsigned long long pr[32];
      bool ok;
      do {
#pragma unroll
        for (int k = 0; k < 32; ++k)
          pr[k] = __hip_atomic_load(&src[cbase + k],
                                    __ATOMIC_RELAXED, __HIP_MEMORY_SCOPE_AGENT);
        ok = true;
#pragma unroll
        for (int k = 0; k < 32; ++k)
          ok &= ((unsigned int)(pr[k] >> 32) == want);
      } while (!ok);

#pragma unroll
      for (int k = 0; k < 32; k += 2) {
        float x0 = __uint_as_float((unsigned int)pr[k]);
        float x1 = __uint_as_float((unsigned int)pr[k + 1]);
        a0 = fmaf(w0[k],     x0, a0);
        a1 = fmaf(w0[k + 1], x1, a1);
        a2 = fmaf(w1[k],     x0, a2);
        a3 = fmaf(w1[k + 1], x1, a3);
      }
    }

    pbuf[pa][c][p]      = a0 + a1;
    pbuf[pa][c][p + 16] = a2 + a3;
    __syncthreads();   // the ONLY barrier per step; parity LDS makes it sufficient

    if (tid < 64) {    // wave 0: reduce 32 chunk-partials per row (16 per half-wave)
      const int half = tid >> 5;
      const int r    = tid & 31;
      float s = 0.f;
#pragma unroll
      for (int cc = 0; cc < 16; ++cc) s += pbuf[pa][cc + 16 * half][r];
      s += __shfl_xor(s, 32);
      if (tid < 32) {
        float x_new = fast_tanh(fmaf(win_r, u_t, s));
        // publish (value, tag=t+1) as one 8B atomic -> self-validating
        unsigned long long packed =
            ((unsigned long long)(unsigned int)(t + 1) << 32) | __float_as_uint(x_new);
        __hip_atomic_store(&(pa ? xb1 : xb0)[g * 32 + r], packed,
                           __ATOMIC_RELAXED, __HIP_MEMORY_SCOPE_AGENT);
        // readout partial (off critical path, fire-and-forget)
        float pv = c_r * x_new;
        pv += __shfl_down(pv, 16, 32);
        pv += __shfl_down(pv,  8, 32);
        pv += __shfl_down(pv,  4, 32);
        pv += __shfl_down(pv,  2, 32);
        pv += __shfl_down(pv,  1, 32);
        if (r == 0 && t >= WASH) atomicAdd(out + (t - WASH), pv);
      }
    }
  }
}

extern "C" void kernel_launch(void* const* d_in, const int* in_sizes, int n_in,
                              void* d_out, int out_size, void* d_ws, size_t ws_size,
                              hipStream_t stream) {
  const float* u     = (const float*)d_in[0];
  const float* w_in  = (const float*)d_in[1];
  const float* w_res = (const float*)d_in[2];
  const float* w_out = (const float*)d_in[3];
  const int*   mask  = (const int*)d_in[4];
  float* out = (float*)d_out;

  // d_out is poisoned 0xAA before every launch; we accumulate into it.
  hipMemsetAsync(out, 0, (size_t)out_size * sizeof(float), stream);

  esn_kernel<<<NWG, NT, 0, stream>>>(u, w_in, w_res, w_out, mask, out,
                                     (unsigned long long*)d_ws);
}

// Round 2
// 135508.496 us; speedup vs baseline: 1.4431x; 1.4431x over previous
//
#include <hip/hip_runtime.h>

// Echo-state network recurrence on MI355X (gfx950).
// Latency-bound: 32 persistent WGs, weights in VGPRs, state exchanged through
// IF$ with self-validating (value,tag) 8B pairs. Round-2 fix: the poll is
// hand-written as 16 batched global_load_dwordx4 sc0 sc1 + ONE s_waitcnt,
// because __hip_atomic_load lowering serialized 32 L3 round trips per poll
// iteration (measured 9400 cyc/step == 32 x ~300 cyc).

#define HH   1024
#define TT   50000
#define WASH 200
#define NWG  32     // WG g owns rows [32g, 32g+32)
#define NT   256    // 4 waves; thread: chunk c=tid>>3 (cols 32c..32c+31), p=tid&7 -> rows p,p+8,p+16,p+24

typedef unsigned int u32;
typedef u32 u32x4 __attribute__((ext_vector_type(4)));

__device__ __forceinline__ float fast_tanh(float x) {
  // tanh(x) = 1 - 2/(exp2(2x*log2e)+1); safe at +/-inf.
  float e = __builtin_amdgcn_exp2f(x * 2.8853900817779268f);
  return fmaf(-2.0f, __builtin_amdgcn_rcpf(e + 1.0f), 1.0f);
}

// Batched coherent 16B load: {val0, tag0, val1, tag1} (two 8B pairs).
#define POLL_LOAD(n, offstr)                                              \
  asm volatile("global_load_dwordx4 %0, %1, off offset:" offstr " sc0 sc1" \
               : "=v"(pr##n) : "v"(src) : "memory")

#define TAGBAD(n) ((pr##n.y ^ want) | (pr##n.w ^ want))

#define FMA2(n)                                                           \
  { float xa = __uint_as_float(pr##n.x);                                  \
    float xb = __uint_as_float(pr##n.z);                                  \
    a0a = fmaf(wr[0][2*n], xa, a0a); a0b = fmaf(wr[0][2*n+1], xb, a0b);   \
    a1a = fmaf(wr[1][2*n], xa, a1a); a1b = fmaf(wr[1][2*n+1], xb, a1b);   \
    a2a = fmaf(wr[2][2*n], xa, a2a); a2b = fmaf(wr[2][2*n+1], xb, a2b);   \
    a3a = fmaf(wr[3][2*n], xa, a3a); a3b = fmaf(wr[3][2*n+1], xb, a3b); }

__global__ __launch_bounds__(NT, 1) void esn_kernel(
    const float* __restrict__ u,
    const float* __restrict__ w_in,
    const float* __restrict__ w_res,
    const float* __restrict__ w_out,
    const int*   __restrict__ mask,
    float*       __restrict__ out,
    unsigned long long* __restrict__ xws)   // 2 * HH tagged pairs (16 KiB)
{
  const int g   = blockIdx.x;
  const int tid = threadIdx.x;
  const int c   = tid >> 3;   // chunk 0..31
  const int p   = tid & 7;    // local row base

  __shared__ float pbuf[2][32][33];  // [parity][chunk][row], +1 pad
  __shared__ float lds_c[HH];

  // readout coefficients: coef[mask[h]] = w_out[h]
  for (int h = tid; h < HH; h += NT) lds_c[mask[h]] = w_out[h];
  __syncthreads();

  // weights resident in VGPRs: 4 rows x 32 cols per thread (128 VGPRs)
  float wr[4][32];
  {
    const int r0 = g * 32 + p;
#pragma unroll
    for (int j = 0; j < 4; ++j) {
      const float4* wp = (const float4*)(w_res + (size_t)(r0 + 8 * j) * HH + c * 32);
#pragma unroll
      for (int q = 0; q < 8; ++q) {
        float4 v = wp[q];
        wr[j][4*q+0] = v.x; wr[j][4*q+1] = v.y;
        wr[j][4*q+2] = v.z; wr[j][4*q+3] = v.w;
      }
    }
  }

  // epilogue-lane preloads (lanes 0..31 of wave 0 own rows g*32+lane)
  float win_r = 0.f, c_r = 0.f;
  if (tid < 32) {
    win_r = w_in[g * 32 + tid];
    c_r   = lds_c[g * 32 + tid];
  }
  __syncthreads();

  unsigned long long* xb0 = xws;        // parity-0 buffer
  unsigned long long* xb1 = xws + HH;   // parity-1 buffer
  unsigned long long* poll0 = xb0 + c * 32;   // poll base, parity source 0
  unsigned long long* poll1 = xb1 + c * 32;   // poll base, parity source 1

  for (int t = 0; t < TT; ++t) {
    const int pa = t & 1;
    const float u_t = u[t];
    float a0a = 0.f, a0b = 0.f, a1a = 0.f, a1b = 0.f;
    float a2a = 0.f, a2b = 0.f, a3a = 0.f, a3b = 0.f;

    if (t > 0) {
      unsigned long long* src = pa ? poll0 : poll1;   // buf[(t-1)&1]
      const u32 want = (u32)t;                        // tag of x_{t-1}
      u32x4 pr0, pr1, pr2, pr3, pr4, pr5, pr6, pr7;
      u32x4 pr8, pr9, pr10, pr11, pr12, pr13, pr14, pr15;
      while (true) {
        POLL_LOAD(0,  "0");   POLL_LOAD(1,  "16");  POLL_LOAD(2,  "32");
        POLL_LOAD(3,  "48");  POLL_LOAD(4,  "64");  POLL_LOAD(5,  "80");
        POLL_LOAD(6,  "96");  POLL_LOAD(7,  "112"); POLL_LOAD(8,  "128");
        POLL_LOAD(9,  "144"); POLL_LOAD(10, "160"); POLL_LOAD(11, "176");
        POLL_LOAD(12, "192"); POLL_LOAD(13, "208"); POLL_LOAD(14, "224");
        POLL_LOAD(15, "240");
        asm volatile("s_waitcnt vmcnt(0)" ::: "memory");
        u32 bad = TAGBAD(0)  | TAGBAD(1)  | TAGBAD(2)  | TAGBAD(3)
                | TAGBAD(4)  | TAGBAD(5)  | TAGBAD(6)  | TAGBAD(7)
                | TAGBAD(8)  | TAGBAD(9)  | TAGBAD(10) | TAGBAD(11)
                | TAGBAD(12) | TAGBAD(13) | TAGBAD(14) | TAGBAD(15);
        if (!bad) break;
      }
      FMA2(0);  FMA2(1);  FMA2(2);  FMA2(3);
      FMA2(4);  FMA2(5);  FMA2(6);  FMA2(7);
      FMA2(8);  FMA2(9);  FMA2(10); FMA2(11);
      FMA2(12); FMA2(13); FMA2(14); FMA2(15);
    }

    pbuf[pa][c][p]      = a0a + a0b;
    pbuf[pa][c][p + 8]  = a1a + a1b;
    pbuf[pa][c][p + 16] = a2a + a2b;
    pbuf[pa][c][p + 24] = a3a + a3b;
    __syncthreads();   // only barrier per step; parity pbuf makes it sufficient

    if (tid < 64) {    // wave 0 reduces: 16 chunks per half-wave, then xor-32
      const int half = tid >> 5;
      const int r    = tid & 31;
      float s = 0.f;
#pragma unroll
      for (int cc = 0; cc < 16; ++cc) s += pbuf[pa][cc + 16 * half][r];
      s += __shfl_xor(s, 32);
      if (tid < 32) {
        float x_new = fast_tanh(fmaf(win_r, u_t, s));
        unsigned long long packed =
            ((unsigned long long)(u32)(t + 1) << 32) | __float_as_uint(x_new);
        unsigned long long* dst = (pa ? xb1 : xb0) + g * 32 + r;
        asm volatile("global_store_dwordx2 %0, %1, off sc0 sc1"
                     :: "v"(dst), "v"(packed) : "memory");
        // readout partial (off critical path)
        float pv = c_r * x_new;
        pv += __shfl_down(pv, 16, 32);
        pv += __shfl_down(pv,  8, 32);
        pv += __shfl_down(pv,  4, 32);
        pv += __shfl_down(pv,  2, 32);
        pv += __shfl_down(pv,  1, 32);
        if (r == 0 && t >= WASH) atomicAdd(out + (t - WASH), pv);
      }
    }
  }
}

extern "C" void kernel_launch(void* const* d_in, const int* in_sizes, int n_in,
                              void* d_out, int out_size, void* d_ws, size_t ws_size,
                              hipStream_t stream) {
  const float* u     = (const float*)d_in[0];
  const float* w_in  = (const float*)d_in[1];
  const float* w_res = (const float*)d_in[2];
  const float* w_out = (const float*)d_in[3];
  const int*   mask  = (const int*)d_in[4];
  float* out = (float*)d_out;

  hipMemsetAsync(out, 0, (size_t)out_size * sizeof(float), stream);

  esn_kernel<<<NWG, NT, 0, stream>>>(u, w_in, w_res, w_out, mask, out,
                                     (unsigned long long*)d_ws);
}

// Round 3
// 87012.177 us; speedup vs baseline: 2.2474x; 1.5574x over previous
//
#include <hip/hip_runtime.h>

// Echo-state network recurrence on MI355X (gfx950).
// Round-3: wave-autonomous. 128 WGs x 64 threads; each wave owns 8 rows with
// weights in VGPRs (wr[8][16]/lane), polls the full 1024-state vector from
// IF$ with self-validating (value,tag) 8B pairs, folds in-register, stores.
// No barriers, no atomics, NO "memory" clobbers (round-2 bug: memory clobbers
// forced per-step weight reloads from L2 -> VGPR_Count 104 instead of ~210).

#define HH   1024
#define TT   50000
#define WASH 200
#define NWG  128
#define NT   64

typedef unsigned int u32;
typedef unsigned long long u64;
typedef u32 u32x4 __attribute__((ext_vector_type(4)));

__device__ __forceinline__ float fast_tanh(float x) {
  // tanh(x) = 1 - 2/(exp2(2x*log2e)+1); safe at +/-inf.
  float e = __builtin_amdgcn_exp2f(x * 2.8853900817779268f);
  return fmaf(-2.0f, __builtin_amdgcn_rcpf(e + 1.0f), 1.0f);
}

// 8 batched coherent 16B loads covering all 1024 (value,tag) pairs, then ONE
// waitcnt that ties the results (ordering via data dependency, not clobbers).
#define POLL_LOAD8(bA, bB)                                                               \
  asm volatile("global_load_dwordx4 %0, %1, off sc0 sc1"             : "=v"(pr0) : "v"(bA)); \
  asm volatile("global_load_dwordx4 %0, %1, off offset:1024 sc0 sc1" : "=v"(pr1) : "v"(bA)); \
  asm volatile("global_load_dwordx4 %0, %1, off offset:2048 sc0 sc1" : "=v"(pr2) : "v"(bA)); \
  asm volatile("global_load_dwordx4 %0, %1, off offset:3072 sc0 sc1" : "=v"(pr3) : "v"(bA)); \
  asm volatile("global_load_dwordx4 %0, %1, off sc0 sc1"             : "=v"(pr4) : "v"(bB)); \
  asm volatile("global_load_dwordx4 %0, %1, off offset:1024 sc0 sc1" : "=v"(pr5) : "v"(bB)); \
  asm volatile("global_load_dwordx4 %0, %1, off offset:2048 sc0 sc1" : "=v"(pr6) : "v"(bB)); \
  asm volatile("global_load_dwordx4 %0, %1, off offset:3072 sc0 sc1" : "=v"(pr7) : "v"(bB)); \
  asm volatile("s_waitcnt vmcnt(0)"                                                      \
               : "+v"(pr0), "+v"(pr1), "+v"(pr2), "+v"(pr3),                             \
                 "+v"(pr4), "+v"(pr5), "+v"(pr6), "+v"(pr7))

#define TAGBAD(n) ((pr##n.y ^ want) | (pr##n.w ^ want))
#define TAGBAD_ALL                                                        \
  (TAGBAD(0) | TAGBAD(1) | TAGBAD(2) | TAGBAD(3) |                        \
   TAGBAD(4) | TAGBAD(5) | TAGBAD(6) | TAGBAD(7))

// lane l, load k covers cols {128k+2l, 128k+2l+1}
#define FMA_K(k)                                                          \
  { float xa = __uint_as_float(pr##k.x);                                  \
    float xb = __uint_as_float(pr##k.z);                                  \
    acc0 = fmaf(wr[0][2*k], xa, acc0); acc0 = fmaf(wr[0][2*k+1], xb, acc0); \
    acc1 = fmaf(wr[1][2*k], xa, acc1); acc1 = fmaf(wr[1][2*k+1], xb, acc1); \
    acc2 = fmaf(wr[2][2*k], xa, acc2); acc2 = fmaf(wr[2][2*k+1], xb, acc2); \
    acc3 = fmaf(wr[3][2*k], xa, acc3); acc3 = fmaf(wr[3][2*k+1], xb, acc3); \
    acc4 = fmaf(wr[4][2*k], xa, acc4); acc4 = fmaf(wr[4][2*k+1], xb, acc4); \
    acc5 = fmaf(wr[5][2*k], xa, acc5); acc5 = fmaf(wr[5][2*k+1], xb, acc5); \
    acc6 = fmaf(wr[6][2*k], xa, acc6); acc6 = fmaf(wr[6][2*k+1], xb, acc6); \
    acc7 = fmaf(wr[7][2*k], xa, acc7); acc7 = fmaf(wr[7][2*k+1], xb, acc7); }

#define RD_K(k)                                                           \
  { y = fmaf(cr[2*k],   __uint_as_float(pr##k.x), y);                     \
    y = fmaf(cr[2*k+1], __uint_as_float(pr##k.z), y); }

__global__ __launch_bounds__(NT, 1) void esn_kernel(
    const float* __restrict__ u,
    const float* __restrict__ w_in,
    const float* __restrict__ w_res,
    const float* __restrict__ w_out,
    const int*   __restrict__ mask,
    float*       __restrict__ out,
    u64*         __restrict__ xws)   // 2 * HH tagged pairs (16 KiB)
{
  const int w = blockIdx.x;    // owns rows [8w, 8w+8)
  const int l = threadIdx.x;   // lane; cols {128k+2l, 128k+2l+1 : k in [0,8)}

  __shared__ float lds_c[HH];
  if (w == 0)
    for (int h = l; h < HH; h += NT) lds_c[mask[h]] = w_out[h];
  __syncthreads();

  // weights resident in VGPRs: 8 rows x 16 cols per lane (128 VGPRs)
  float wr[8][16];
#pragma unroll
  for (int r = 0; r < 8; ++r) {
    const float2* wp = (const float2*)(w_res + (size_t)(8 * w + r) * HH) + l;
#pragma unroll
    for (int k = 0; k < 8; ++k) {
      float2 v = wp[64 * k];
      wr[r][2 * k] = v.x; wr[r][2 * k + 1] = v.y;
    }
  }

  // lane (l&7)==0 stores row 8w + (l>>3); preload its w_in coefficient
  const float win = w_in[8 * w + (l >> 3)];

  // readout coefficients for WG 0's wave only
  float cr[16];
  if (w == 0) {
#pragma unroll
    for (int k = 0; k < 8; ++k) {
      float2 v = ((const float2*)lds_c)[64 * k + l];
      cr[2 * k] = v.x; cr[2 * k + 1] = v.y;
    }
  } else {
#pragma unroll
    for (int k = 0; k < 16; ++k) cr[k] = 0.f;
  }

  u64* xb0 = xws;        // parity-0 buffer (x_t for even t)
  u64* xb1 = xws + HH;   // parity-1 buffer
  const u64* pA0 = xb0 + 2 * l;        // poll bases (lane-interleaved granules)
  const u64* pB0 = pA0 + 512;
  const u64* pA1 = xb1 + 2 * l;
  const u64* pB1 = pA1 + 512;
  const int drow = 8 * w + (l >> 3);
  u64* d0 = xb0 + drow;
  u64* d1 = xb1 + drow;

  u32x4 pr0, pr1, pr2, pr3, pr4, pr5, pr6, pr7;
  const int lb32 = l & 32, lb16 = l & 16, lb8 = l & 8;

  for (int t = 0; t < TT; ++t) {
    const int pa = t & 1;
    const float u_t = u[t];
    float acc0 = 0.f, acc1 = 0.f, acc2 = 0.f, acc3 = 0.f;
    float acc4 = 0.f, acc5 = 0.f, acc6 = 0.f, acc7 = 0.f;

    if (t > 0) {
      const u64* bA = pa ? pA0 : pA1;   // source = buf[(t-1)&1]
      const u64* bB = pa ? pB0 : pB1;
      const u32 want = (u32)t;          // tag of x_{t-1}
      while (true) {
        POLL_LOAD8(bA, bB);
        if (!TAGBAD_ALL) break;
      }
      FMA_K(0); FMA_K(1); FMA_K(2); FMA_K(3);
      FMA_K(4); FMA_K(5); FMA_K(6); FMA_K(7);
    }

    // fold 64 lanes x 8 values -> value v=(4*b5+2*b4+b3) full sum on lanes l
    float t0 = (lb32 ? acc4 : acc0) + __shfl_xor(lb32 ? acc0 : acc4, 32);
    float t1 = (lb32 ? acc5 : acc1) + __shfl_xor(lb32 ? acc1 : acc5, 32);
    float t2 = (lb32 ? acc6 : acc2) + __shfl_xor(lb32 ? acc2 : acc6, 32);
    float t3 = (lb32 ? acc7 : acc3) + __shfl_xor(lb32 ? acc3 : acc7, 32);
    float s0 = (lb16 ? t2 : t0) + __shfl_xor(lb16 ? t0 : t2, 16);
    float s1 = (lb16 ? t3 : t1) + __shfl_xor(lb16 ? t1 : t3, 16);
    float r0 = (lb8 ? s1 : s0) + __shfl_xor(lb8 ? s0 : s1, 8);
    r0 += __shfl_xor(r0, 4);
    r0 += __shfl_xor(r0, 2);
    r0 += __shfl_xor(r0, 1);

    float x_new = fast_tanh(fmaf(win, u_t, r0));
    u64 packed = ((u64)(u32)(t + 1) << 32) | __float_as_uint(x_new);
    if ((l & 7) == 0) {
      u64* dst = pa ? d1 : d0;          // dest = buf[t&1]
      asm volatile("global_store_dwordx2 %0, %1, off sc0 sc1"
                   :: "v"(dst), "v"(packed));
    }

    // readout y_{t-1} from this step's polled registers (WG 0 only, off path)
    if (w == 0 && t > 0) {
      float y = 0.f;
      RD_K(0); RD_K(1); RD_K(2); RD_K(3);
      RD_K(4); RD_K(5); RD_K(6); RD_K(7);
      y += __shfl_xor(y, 32); y += __shfl_xor(y, 16); y += __shfl_xor(y, 8);
      y += __shfl_xor(y, 4);  y += __shfl_xor(y, 2);  y += __shfl_xor(y, 1);
      if (l == 0 && t - 1 >= WASH) out[t - 1 - WASH] = y;
    }
  }

  // final readout: x_{TT-1} was stored but never polled in-loop
  if (w == 0) {
    const u32 want = (u32)TT;           // x_{TT-1} lives in buf[(TT-1)&1]=buf[1]
    while (true) {
      POLL_LOAD8(pA1, pB1);
      if (!TAGBAD_ALL) break;
    }
    float y = 0.f;
    RD_K(0); RD_K(1); RD_K(2); RD_K(3);
    RD_K(4); RD_K(5); RD_K(6); RD_K(7);
    y += __shfl_xor(y, 32); y += __shfl_xor(y, 16); y += __shfl_xor(y, 8);
    y += __shfl_xor(y, 4);  y += __shfl_xor(y, 2);  y += __shfl_xor(y, 1);
    if (l == 0) out[TT - 1 - WASH] = y;
  }
}

extern "C" void kernel_launch(void* const* d_in, const int* in_sizes, int n_in,
                              void* d_out, int out_size, void* d_ws, size_t ws_size,
                              hipStream_t stream) {
  const float* u     = (const float*)d_in[0];
  const float* w_in  = (const float*)d_in[1];
  const float* w_res = (const float*)d_in[2];
  const float* w_out = (const float*)d_in[3];
  const int*   mask  = (const int*)d_in[4];
  float* out = (float*)d_out;

  // every out element is written exactly once by WG 0 -> no memset needed
  esn_kernel<<<NWG, NT, 0, stream>>>(u, w_in, w_res, w_out, mask, out,
                                     (u64*)d_ws);
}